// Round 10
// baseline (278.641 us; speedup 1.0000x reference)
//
#include <hip/hip_runtime.h>
#include <hip/hip_bf16.h>

#define B_ 4
#define S_ 4096
#define D_ 256
#define BM 128
#define BN 32
#define NSPLIT 4
#define SKEYS (S_/NSPLIT)   // 1024 keys per split
#define ITERS (SKEYS/BN)    // 32

typedef short v8s __attribute__((ext_vector_type(8)));
typedef float v16f __attribute__((ext_vector_type(16)));
typedef unsigned int v4u __attribute__((ext_vector_type(4)));

__device__ __forceinline__ unsigned int pkb(float a, float b){
    __hip_bfloat162 h = __float22bfloat162_rn(make_float2(a, b));   // packed cvt
    union { __hip_bfloat162 h; unsigned int u; } c; c.h = h;
    return c.u;               // a in low 16, b in high 16
}
__device__ __forceinline__ float bf2f(unsigned int lo16){
    return __uint_as_float(lo16 << 16);
}
// async global->LDS, 16B/lane; LDS dest = wave-uniform base + lane*16
__device__ __forceinline__ void gload_lds(const unsigned short* g, unsigned short* l){
    __builtin_amdgcn_global_load_lds(
        (const __attribute__((address_space(1))) unsigned int*)g,
        (__attribute__((address_space(3))) unsigned int*)l, 16, 0, 0);
}

// ---------- fused conversion to tile-major bf16 (LDS-transposed, coalesced) ----------
// 1536 blocks x 256 threads; block = one 32-row tile of one matrix.
//   bx[0..511]    : Q tile  (pre-scaled by log2e/16), layout [c 0..31][row 0..31] 16B cells
//   bx[512..1023] : K tile  (same layout)
//   bx[1024..1535]: V tile  (layout [kc 0..3][d 0..255] 16B cells, cell = 8 keys at one d)
__global__ void cvt_all(const float* __restrict__ q, const float* __restrict__ k,
                        const float* __restrict__ v,
                        uint4* __restrict__ qb, uint4* __restrict__ kb,
                        uint4* __restrict__ vt){
    __shared__ __align__(16) unsigned short lds[8192];   // 16KB: one bf16 tile
    int bx = blockIdx.x;
    int t  = threadIdx.x;
    int which = bx >> 9;            // 0=Q, 1=K, 2=V
    int tile  = bx & 511;
    const float* srcm = (which == 0) ? q : (which == 1) ? k : v;
    const float4* src = (const float4*)(srcm + (size_t)tile * 8192);

    if (which < 2){
        const float sc = (which == 0) ? 0.09016994f : 1.0f;   // log2(e)/16 for Q
        // phase 1: row-major bf16 into LDS, swizzled byte ^= (row&7)<<4
        #pragma unroll
        for (int p = 0; p < 8; ++p){
            int i = p*256 + t;                 // float4 index, coalesced
            float4 a = src[i];
            int row = i >> 6, d0 = (i & 63) * 4;
            unsigned byte = (unsigned)(row*512 + d0*2) ^ (unsigned)((row & 7) << 4);
            uint2 u; u.x = pkb(a.x*sc, a.y*sc); u.y = pkb(a.z*sc, a.w*sc);
            *(uint2*)((char*)lds + byte) = u;
        }
        __syncthreads();
        // phase 2: cell o = c*32 + row; consecutive threads -> consecutive cells
        uint4* dst = ((which == 0) ? qb : kb) + (size_t)tile * 1024;
        #pragma unroll
        for (int q4 = 0; q4 < 4; ++q4){
            int o = q4*256 + t;
            int c = o >> 5, row = o & 31;
            unsigned byte = (unsigned)(row*512 + c*16) ^ (unsigned)((row & 7) << 4);
            dst[o] = *(const uint4*)((const char*)lds + byte);
        }
    } else {
        // phase 1: row-major bf16 into LDS, linear
        #pragma unroll
        for (int p = 0; p < 8; ++p){
            int i = p*256 + t;
            float4 a = src[i];
            uint2 u; u.x = pkb(a.x, a.y); u.y = pkb(a.z, a.w);
            *(uint2*)((char*)lds + (size_t)i*8) = u;
        }
        __syncthreads();
        // phase 2: cell o = kc*256 + d; content[j] = V[kc*8+j][d]
        uint4* dst = vt + (size_t)tile * 1024;
        #pragma unroll
        for (int q4 = 0; q4 < 4; ++q4){          // kc = q4, d = t
            union { unsigned short sh[8]; uint4 u; } cell;
            #pragma unroll
            for (int j = 0; j < 8; ++j)
                cell.sh[j] = lds[(q4*8 + j)*256 + t];
            dst[q4*256 + t] = cell.u;
        }
    }
}

// ---------- main flash-attention kernel (merge fused, RELAXED-poll protocol) ----------
// Compute loop identical to round 9 (PV pipelined one iter, interleaved MFMA,
// K/V LDS dbuf, counted vmcnt, setprio).
// Merge fusion (r8 protocol, r8 bug fixed): splits 0-2 store bf16 O to opart,
// release-fence, atomicAdd cnt. Split 3 keeps O in regs and SPINS WITH RELAXED
// loads (no per-poll L2 invalidate — r8's acquire-polling invalidated the XCD
// L2 every poll, evicting the K/V stream of 32 co-resident blocks: FETCH +14MB,
// HBM 170GB/s, 2.3x slowdown). One acquire fence after cnt==3, then merge +
// f32 out write. Deadlock-free: split 3 waits only on splits 0-2 (never wait);
// all 512 blocks co-resident at 2/CU.
__global__ __launch_bounds__(256, 2) void fa_main(
    const unsigned short* __restrict__ qb, const unsigned short* __restrict__ kb,
    const unsigned short* __restrict__ vtg,
    unsigned short* __restrict__ opart, float* __restrict__ lsep,
    float* __restrict__ out, unsigned int* cnt)
{
    // LDS: K0 | K1 | V0 | V1, 8192 shorts (16KB) each = 64KB.
    // Epilogue scratch reuses [0, 16640) shorts; final PV reads V1 (24576+) — no overlap.
    __shared__ __align__(16) unsigned short sbuf[32768];

    int bid = blockIdx.x;
    int grp = bid & 15;                 // (b,split): KV group -> XCD slot
    int qt  = bid >> 4;
    int b = grp >> 2, split = grp & 3;
    int tid = threadIdx.x;
    int w = tid >> 6, lane = tid & 63, hi = lane >> 5, ln = lane & 31;

    const unsigned short* kg = kb + ((size_t)(b*128 + split*32))*8192;
    const unsigned short* vg = vtg + ((size_t)(b*128 + split*32))*8192;

    auto stageK = [&](int tile, int buf){
        const unsigned short* src = kg + (size_t)tile*8192 + w*2048;
        #pragma unroll
        for (int p = 0; p < 4; ++p)
            gload_lds(src + p*512 + lane*8, &sbuf[buf*8192 + w*2048 + p*512 + lane*8]);
    };
    auto stageV = [&](int tile, int buf){
        const unsigned short* src = vg + (size_t)tile*8192 + w*2048;
        #pragma unroll
        for (int p = 0; p < 4; ++p)
            gload_lds(src + p*512 + lane*8, &sbuf[16384 + buf*8192 + w*2048 + p*512 + lane*8]);
    };

    // Q direct global->reg: contiguous, coalesced 16B/lane fragment spans
    v8s qf[16];
    {
        const unsigned short* qsrc = qb + ((size_t)(b*128 + qt*4 + w))*8192;
        #pragma unroll
        for (int f = 0; f < 16; ++f)
            qf[f] = *(const v8s*)&qsrc[(2*f + hi)*256 + ln*8];
    }
    stageK(0, 0);
    stageV(0, 0);
    asm volatile("s_waitcnt vmcnt(0)" ::: "memory");
    __builtin_amdgcn_sched_barrier(0);
    __builtin_amdgcn_s_barrier();      // K(0), V(0) resident for all waves

    v16f oacc[8];
    #pragma unroll
    for (int t = 0; t < 8; ++t)
        #pragma unroll
        for (int r = 0; r < 16; ++r) oacc[t][r] = 0.0f;
    float l_run = 0.0f;
    v8s pf_prev[2] = {};               // set in iter 0, consumed from iter 1

    for (int it = 0; it < ITERS; ++it){
        int cur = it & 1;
        const unsigned short* Kb    = &sbuf[cur*8192];
        const unsigned short* Vprev = &sbuf[16384 + (cur ^ 1)*8192];   // (it-1)&1

        if (it + 1 < ITERS) stageK(it + 1, cur ^ 1);

        // ---- INTERLEAVED MFMA region: QK(it) + PV(it-1) ----
        v16f sa, sb;
        #pragma unroll
        for (int r = 0; r < 16; ++r){ sa[r] = 0.0f; sb[r] = 0.0f; }
        __builtin_amdgcn_s_setprio(1);
        #pragma unroll
        for (int f = 0; f < 8; ++f){
            v8s a0 = *(const v8s*)&Kb[(2*f      + hi)*256 + ln*8];
            v8s a1 = *(const v8s*)&Kb[(2*(f+8) + hi)*256 + ln*8];
            sa = __builtin_amdgcn_mfma_f32_32x32x16_bf16(a0, qf[f],   sa, 0, 0, 0);
            sb = __builtin_amdgcn_mfma_f32_32x32x16_bf16(a1, qf[f+8], sb, 0, 0, 0);
            if (it > 0){
                v8s av0 = *(const v8s*)&Vprev[(hi    )*2048 + ln*8 + f*256];
                v8s av1 = *(const v8s*)&Vprev[(2 + hi)*2048 + ln*8 + f*256];
                oacc[f] = __builtin_amdgcn_mfma_f32_32x32x16_bf16(av0, pf_prev[0], oacc[f], 0, 0, 0);
                oacc[f] = __builtin_amdgcn_mfma_f32_32x32x16_bf16(av1, pf_prev[1], oacc[f], 0, 0, 0);
            }
        }
        __builtin_amdgcn_s_setprio(0);
        v16f sc2;
        #pragma unroll
        for (int r = 0; r < 16; ++r) sc2[r] = sa[r] + sb[r];

        // ---- bar1: Vbuf((it-1)&1) readers done -> safe to restage ----
        __builtin_amdgcn_s_barrier();
        if (it + 1 < ITERS) stageV(it + 1, cur ^ 1);

        // ---- fixed-base softmax: P = exp2(S) ----
        float ls = 0.0f;
        uint2 pA[4];
        #pragma unroll
        for (int c = 0; c < 4; ++c){
            float e0 = exp2f(sc2[4*c+0]), e1 = exp2f(sc2[4*c+1]);
            float e2 = exp2f(sc2[4*c+2]), e3 = exp2f(sc2[4*c+3]);
            ls += (e0 + e1) + (e2 + e3);
            pA[c].x = pkb(e0, e1); pA[c].y = pkb(e2, e3);
        }
        ls += __shfl_xor(ls, 32);
        l_run += ls;

        // ---- P: C-layout -> B-operand via lane^32 quad exchange ----
        #pragma unroll
        for (int ks = 0; ks < 2; ++ks){
            uint2 snd = pA[2*ks + 1 - hi];
            uint2 rcv;
            rcv.x = (unsigned int)__shfl_xor((int)snd.x, 32);
            rcv.y = (unsigned int)__shfl_xor((int)snd.y, 32);
            uint2 lo = hi ? rcv : pA[2*ks];
            uint2 hb = hi ? pA[2*ks+1] : rcv;
            union { unsigned int u[4]; v8s vv; } cc;
            cc.u[0] = lo.x; cc.u[1] = lo.y; cc.u[2] = hb.x; cc.u[3] = hb.y;
            pf_prev[ks] = cc.vv;
        }

        // ---- bar2: counted wait — K(it+1) resident, V(it+1) in flight ----
        if (it == ITERS - 1) asm volatile("s_waitcnt vmcnt(0)" ::: "memory");
        else                 asm volatile("s_waitcnt vmcnt(4)" ::: "memory");
        __builtin_amdgcn_sched_barrier(0);
        __builtin_amdgcn_s_barrier();
    }

    // ---- final PV(ITERS-1): V in Vbuf((ITERS-1)&1) = Vbuf1 ----
    {
        const unsigned short* Vlast = &sbuf[16384 + ((ITERS - 1) & 1)*8192];
        __builtin_amdgcn_s_setprio(1);
        #pragma unroll
        for (int ks = 0; ks < 2; ++ks){
            const unsigned short* vrow = &Vlast[(2*ks + hi)*2048 + ln*8];
            #pragma unroll
            for (int t2 = 0; t2 < 8; ++t2){
                v8s av = *(const v8s*)&vrow[t2*256];
                oacc[t2] = __builtin_amdgcn_mfma_f32_32x32x16_bf16(av, pf_prev[ks], oacc[t2], 0, 0, 0);
            }
        }
        __builtin_amdgcn_s_setprio(0);
    }

    // ---- epilogue ----
    float inv = 1.0f / l_run;
    size_t orow0 = (size_t)(split*B_ + b)*S_ + qt*BM + w*32;   // lsep row (split-major)
    if (hi == 0) lsep[orow0 + ln] = l_run;
    int cidx = b*32 + qt;

    unsigned short* myreg = &sbuf[(w & 1) * 8320];       // 32 rows x 260 shorts

    if (split < 3){
        // ---- producers: normalize, transpose, store bf16 O to opart, signal ----
        #pragma unroll
        for (int rnd = 0; rnd < 2; ++rnd){
            __syncthreads();
            if ((w >> 1) == rnd){
                #pragma unroll
                for (int t = 0; t < 8; ++t)
                    #pragma unroll
                    for (int g = 0; g < 4; ++g){
                        uint2 u;
                        u.x = pkb(oacc[t][4*g+0]*inv, oacc[t][4*g+1]*inv);
                        u.y = pkb(oacc[t][4*g+2]*inv, oacc[t][4*g+3]*inv);
                        *(uint2*)&myreg[ln*260 + t*32 + 8*g + 4*hi] = u;
                    }
                #pragma unroll
                for (int p = 0; p < 16; ++p){
                    int qq = 2*p + (lane >> 5);
                    int ch = lane & 31;
                    v4u val = *(const v4u*)&myreg[qq*260 + ch*8];
                    *(v4u*)(opart + (orow0 + qq)*D_ + ch*8) = val;
                }
            }
        }
        __syncthreads();                 // all waves' stores drained (vmcnt 0)
        __threadfence();                 // release: device-visible
        if (tid == 0) atomicAdd(&cnt[cidx], 1u);
    } else {
        // ---- merger (split 3): own O stays in registers; wait for producers ----
        // RELAXED polls (no L2 invalidate per poll); single acquire fence after.
        if (tid == 0){
            while (__hip_atomic_load(&cnt[cidx], __ATOMIC_RELAXED,
                                     __HIP_MEMORY_SCOPE_AGENT) < 3u)
                __builtin_amdgcn_s_sleep(8);
        }
        __syncthreads();
        __threadfence();                 // acquire: one L2 invalidate, then read

        size_t brow = (size_t)b*S_ + qt*BM + w*32;       // out row base (no split dim)
        #pragma unroll
        for (int rnd = 0; rnd < 2; ++rnd){
            __syncthreads();
            if ((w >> 1) == rnd){
                // transpose own normalized O into LDS (identical to producers)
                #pragma unroll
                for (int t = 0; t < 8; ++t)
                    #pragma unroll
                    for (int g = 0; g < 4; ++g){
                        uint2 u;
                        u.x = pkb(oacc[t][4*g+0]*inv, oacc[t][4*g+1]*inv);
                        u.y = pkb(oacc[t][4*g+2]*inv, oacc[t][4*g+3]*inv);
                        *(uint2*)&myreg[ln*260 + t*32 + 8*g + 4*hi] = u;
                    }
                // read back + merge with splits 0-2 + write f32 out (coalesced)
                #pragma unroll
                for (int p = 0; p < 16; ++p){
                    int qq = 2*p + (lane >> 5);
                    int ch = lane & 31;
                    v4u val = *(const v4u*)&myreg[qq*260 + ch*8];
                    size_t row = brow + qq;
                    float L0 = lsep[row];
                    float L1 = lsep[(size_t)(B_*S_)   + row];
                    float L2 = lsep[(size_t)(2*B_*S_) + row];
                    float L3 = lsep[(size_t)(3*B_*S_) + row];
                    float winv = 1.0f / (L0 + L1 + L2 + L3);
                    float w3 = L3 * winv;
                    float accv[8];
                    accv[0] = w3*bf2f(val.x & 0xffffu);  accv[1] = w3*bf2f(val.x >> 16);
                    accv[2] = w3*bf2f(val.y & 0xffffu);  accv[3] = w3*bf2f(val.y >> 16);
                    accv[4] = w3*bf2f(val.z & 0xffffu);  accv[5] = w3*bf2f(val.z >> 16);
                    accv[6] = w3*bf2f(val.w & 0xffffu);  accv[7] = w3*bf2f(val.w >> 16);
                    float Ls[3] = {L0, L1, L2};
                    #pragma unroll
                    for (int s = 0; s < 3; ++s){
                        float ws = Ls[s] * winv;
                        uint4 u = *(const uint4*)(opart
                                  + ((size_t)s*(B_*S_) + row)*D_ + ch*8);
                        accv[0] += ws*bf2f(u.x & 0xffffu);  accv[1] += ws*bf2f(u.x >> 16);
                        accv[2] += ws*bf2f(u.y & 0xffffu);  accv[3] += ws*bf2f(u.y >> 16);
                        accv[4] += ws*bf2f(u.z & 0xffffu);  accv[5] += ws*bf2f(u.z >> 16);
                        accv[6] += ws*bf2f(u.w & 0xffffu);  accv[7] += ws*bf2f(u.w >> 16);
                    }
                    float* op = out + row*D_ + ch*8;
                    *(float4*)op       = make_float4(accv[0], accv[1], accv[2], accv[3]);
                    *(float4*)(op + 4) = make_float4(accv[4], accv[5], accv[6], accv[7]);
                }
            }
        }
    }
}

extern "C" void kernel_launch(void* const* d_in, const int* in_sizes, int n_in,
                              void* d_out, int out_size, void* d_ws, size_t ws_size,
                              hipStream_t stream){
    const float* q = (const float*)d_in[0];
    const float* k = (const float*)d_in[1];
    const float* v = (const float*)d_in[2];
    char* ws = (char*)d_ws;
    // ws: Qb 8M | Kb 8M | Vt 8M | lse 256K | cnt 4K | Opart(bf16, 3 splits) 24M
    //   = 50,597,888 B
    uint4* qb = (uint4*)(ws);
    uint4* kb = (uint4*)(ws + 8388608);
    uint4* vt = (uint4*)(ws + 16777216);
    float* lse = (float*)(ws + 25165824);
    unsigned int* cnt = (unsigned int*)(ws + 25427968);
    unsigned short* opart = (unsigned short*)(ws + 25432064);

    hipMemsetAsync(cnt, 0, 4096, stream);
    cvt_all<<<dim3(1536), dim3(256), 0, stream>>>(q, k, v, qb, kb, vt);
    fa_main<<<dim3(512), dim3(256), 0, stream>>>((const unsigned short*)qb,
                                                 (const unsigned short*)kb,
                                                 (const unsigned short*)vt,
                                                 opart, lse, (float*)d_out, cnt);
}

// Round 11
// 201.391 us; speedup vs baseline: 1.3836x; 1.3836x over previous
//
#include <hip/hip_runtime.h>
#include <hip/hip_bf16.h>

#define B_ 4
#define S_ 4096
#define D_ 256
#define BM 128
#define BN 32
#define NSPLIT 4
#define SKEYS (S_/NSPLIT)   // 1024 keys per split
#define ITERS (SKEYS/BN)    // 32

typedef short v8s __attribute__((ext_vector_type(8)));
typedef float v16f __attribute__((ext_vector_type(16)));
typedef unsigned int v4u __attribute__((ext_vector_type(4)));

__device__ __forceinline__ unsigned int pkb(float a, float b){
    __hip_bfloat162 h = __float22bfloat162_rn(make_float2(a, b));   // packed cvt
    union { __hip_bfloat162 h; unsigned int u; } c; c.h = h;
    return c.u;               // a in low 16, b in high 16
}
__device__ __forceinline__ float bf2f(unsigned int lo16){
    return __uint_as_float(lo16 << 16);
}
// async global->LDS, 16B/lane; LDS dest = wave-uniform base + lane*16
__device__ __forceinline__ void gload_lds(const unsigned short* g, unsigned short* l){
    __builtin_amdgcn_global_load_lds(
        (const __attribute__((address_space(1))) unsigned int*)g,
        (__attribute__((address_space(3))) unsigned int*)l, 16, 0, 0);
}

// ---------- fused conversion to tile-major bf16 (LDS-transposed, coalesced) ----------
// 1536 blocks x 256 threads; block = one 32-row tile of one matrix.
//   bx[0..511]    : Q tile  (pre-scaled by log2e/16), layout [c 0..31][row 0..31] 16B cells
//   bx[512..1023] : K tile  (same layout)
//   bx[1024..1535]: V tile  (layout [kc 0..3][d 0..255] 16B cells, cell = 8 keys at one d)
__global__ void cvt_all(const float* __restrict__ q, const float* __restrict__ k,
                        const float* __restrict__ v,
                        uint4* __restrict__ qb, uint4* __restrict__ kb,
                        uint4* __restrict__ vt){
    __shared__ __align__(16) unsigned short lds[8192];   // 16KB: one bf16 tile
    int bx = blockIdx.x;
    int t  = threadIdx.x;
    int which = bx >> 9;            // 0=Q, 1=K, 2=V
    int tile  = bx & 511;
    const float* srcm = (which == 0) ? q : (which == 1) ? k : v;
    const float4* src = (const float4*)(srcm + (size_t)tile * 8192);

    if (which < 2){
        const float sc = (which == 0) ? 0.09016994f : 1.0f;   // log2(e)/16 for Q
        // phase 1: row-major bf16 into LDS, swizzled byte ^= (row&7)<<4
        #pragma unroll
        for (int p = 0; p < 8; ++p){
            int i = p*256 + t;                 // float4 index, coalesced
            float4 a = src[i];
            int row = i >> 6, d0 = (i & 63) * 4;
            unsigned byte = (unsigned)(row*512 + d0*2) ^ (unsigned)((row & 7) << 4);
            uint2 u; u.x = pkb(a.x*sc, a.y*sc); u.y = pkb(a.z*sc, a.w*sc);
            *(uint2*)((char*)lds + byte) = u;
        }
        __syncthreads();
        // phase 2: cell o = c*32 + row; consecutive threads -> consecutive cells
        uint4* dst = ((which == 0) ? qb : kb) + (size_t)tile * 1024;
        #pragma unroll
        for (int q4 = 0; q4 < 4; ++q4){
            int o = q4*256 + t;
            int c = o >> 5, row = o & 31;
            unsigned byte = (unsigned)(row*512 + c*16) ^ (unsigned)((row & 7) << 4);
            dst[o] = *(const uint4*)((const char*)lds + byte);
        }
    } else {
        // phase 1: row-major bf16 into LDS, linear
        #pragma unroll
        for (int p = 0; p < 8; ++p){
            int i = p*256 + t;
            float4 a = src[i];
            uint2 u; u.x = pkb(a.x, a.y); u.y = pkb(a.z, a.w);
            *(uint2*)((char*)lds + (size_t)i*8) = u;
        }
        __syncthreads();
        // phase 2: cell o = kc*256 + d; content[j] = V[kc*8+j][d]
        uint4* dst = vt + (size_t)tile * 1024;
        #pragma unroll
        for (int q4 = 0; q4 < 4; ++q4){          // kc = q4, d = t
            union { unsigned short sh[8]; uint4 u; } cell;
            #pragma unroll
            for (int j = 0; j < 8; ++j)
                cell.sh[j] = lds[(q4*8 + j)*256 + t];
            dst[q4*256 + t] = cell.u;
        }
    }
}

// ---------- main flash-attention kernel ----------
// 4 waves; wave owns 32 queries x all 32 keys/iter x full d=256.
// r9 structure (PV software-pipelined one iter, K/V LDS dbuf, counted vmcnt)
// with the MIXED REGION: PV(it-1) MFMAs interleaved 2:2:1 with softmax(it)
// exp2/pack VALU. The two are mutually independent (softmax reads sc2 from
// QK(it); PV reads pf_prev + V(it-1)), so the VALU slice issues into the
// matrix pipe's shadow instead of serializing after it.
// ls summation tree and per-element accumulation order preserved exactly ->
// bit-identical output.
__global__ __launch_bounds__(256, 2) void fa_main(
    const unsigned short* __restrict__ qb, const unsigned short* __restrict__ kb,
    const unsigned short* __restrict__ vtg,
    unsigned short* __restrict__ opart, float* __restrict__ lsep)
{
    // LDS: K0 | K1 | V0 | V1, 8192 shorts (16KB) each = 64KB.
    // Epilogue scratch reuses [0, 16640) shorts; final PV reads V1 (24576+) — no overlap.
    __shared__ __align__(16) unsigned short sbuf[32768];

    int bid = blockIdx.x;
    int grp = bid & 15;                 // (b,split): KV group -> XCD slot
    int qt  = bid >> 4;
    int b = grp >> 2, split = grp & 3;
    int tid = threadIdx.x;
    int w = tid >> 6, lane = tid & 63, hi = lane >> 5, ln = lane & 31;

    const unsigned short* kg = kb + ((size_t)(b*128 + split*32))*8192;
    const unsigned short* vg = vtg + ((size_t)(b*128 + split*32))*8192;

    auto stageK = [&](int tile, int buf){
        const unsigned short* src = kg + (size_t)tile*8192 + w*2048;
        #pragma unroll
        for (int p = 0; p < 4; ++p)
            gload_lds(src + p*512 + lane*8, &sbuf[buf*8192 + w*2048 + p*512 + lane*8]);
    };
    auto stageV = [&](int tile, int buf){
        const unsigned short* src = vg + (size_t)tile*8192 + w*2048;
        #pragma unroll
        for (int p = 0; p < 4; ++p)
            gload_lds(src + p*512 + lane*8, &sbuf[16384 + buf*8192 + w*2048 + p*512 + lane*8]);
    };

    // Q direct global->reg: contiguous, coalesced 16B/lane fragment spans
    v8s qf[16];
    {
        const unsigned short* qsrc = qb + ((size_t)(b*128 + qt*4 + w))*8192;
        #pragma unroll
        for (int f = 0; f < 16; ++f)
            qf[f] = *(const v8s*)&qsrc[(2*f + hi)*256 + ln*8];
    }
    stageK(0, 0);
    stageV(0, 0);
    asm volatile("s_waitcnt vmcnt(0)" ::: "memory");
    __builtin_amdgcn_sched_barrier(0);
    __builtin_amdgcn_s_barrier();      // K(0), V(0) resident for all waves

    v16f oacc[8];
    #pragma unroll
    for (int t = 0; t < 8; ++t)
        #pragma unroll
        for (int r = 0; r < 16; ++r) oacc[t][r] = 0.0f;
    float l_run = 0.0f;
    v8s pf_prev[2] = {};               // set in iter 0, consumed from iter 1

    for (int it = 0; it < ITERS; ++it){
        int cur = it & 1;
        const unsigned short* Kb    = &sbuf[cur*8192];
        const unsigned short* Vprev = &sbuf[16384 + (cur ^ 1)*8192];   // (it-1)&1

        if (it + 1 < ITERS) stageK(it + 1, cur ^ 1);

        // ---- QK(it): S^T = K·Q^T ----
        v16f sa, sb;
        #pragma unroll
        for (int r = 0; r < 16; ++r){ sa[r] = 0.0f; sb[r] = 0.0f; }
        __builtin_amdgcn_s_setprio(1);
        #pragma unroll
        for (int f = 0; f < 8; ++f){
            v8s a0 = *(const v8s*)&Kb[(2*f      + hi)*256 + ln*8];
            v8s a1 = *(const v8s*)&Kb[(2*(f+8) + hi)*256 + ln*8];
            sa = __builtin_amdgcn_mfma_f32_32x32x16_bf16(a0, qf[f],   sa, 0, 0, 0);
            sb = __builtin_amdgcn_mfma_f32_32x32x16_bf16(a1, qf[f+8], sb, 0, 0, 0);
        }
        __builtin_amdgcn_s_setprio(0);
        v16f sc2;
        #pragma unroll
        for (int r = 0; r < 16; ++r) sc2[r] = sa[r] + sb[r];

        // ---- MIXED REGION: PV(it-1) MFMA ∥ softmax(it) VALU, per f-step:
        //      2 PV MFMAs + 2 exp2 + 1 pack. Independent chains; no
        //      sched_barrier inside so the scheduler can co-issue. ----
        float tpair[8];
        uint2 pA[4];
        __builtin_amdgcn_s_setprio(1);
        #pragma unroll
        for (int f = 0; f < 8; ++f){
            if (it > 0){
                v8s av0 = *(const v8s*)&Vprev[(hi    )*2048 + ln*8 + f*256];
                v8s av1 = *(const v8s*)&Vprev[(2 + hi)*2048 + ln*8 + f*256];
                oacc[f] = __builtin_amdgcn_mfma_f32_32x32x16_bf16(av0, pf_prev[0], oacc[f], 0, 0, 0);
                oacc[f] = __builtin_amdgcn_mfma_f32_32x32x16_bf16(av1, pf_prev[1], oacc[f], 0, 0, 0);
            }
            float e0 = exp2f(sc2[2*f + 0]), e1 = exp2f(sc2[2*f + 1]);
            tpair[f] = e0 + e1;
            unsigned pk = pkb(e0, e1);
            if (f & 1) pA[f >> 1].y = pk; else pA[f >> 1].x = pk;
        }
        __builtin_amdgcn_s_setprio(0);
        // ls tree identical to r9: ls += (pair(4c)+pair(4c+1)) per c, sequential
        float ls = 0.0f;
        #pragma unroll
        for (int c = 0; c < 4; ++c) ls += tpair[2*c] + tpair[2*c + 1];
        ls += __shfl_xor(ls, 32);
        l_run += ls;

        // ---- bar1: all waves finished PV reads of Vbuf((it-1)&1) -> restage ----
        __builtin_amdgcn_s_barrier();
        if (it + 1 < ITERS) stageV(it + 1, cur ^ 1);

        // ---- P: C-layout -> B-operand via lane^32 quad exchange -> pf_prev ----
        // (pf_prev overwritten only AFTER the mixed region consumed it)
        #pragma unroll
        for (int ks = 0; ks < 2; ++ks){
            uint2 snd = pA[2*ks + 1 - hi];
            uint2 rcv;
            rcv.x = (unsigned int)__shfl_xor((int)snd.x, 32);
            rcv.y = (unsigned int)__shfl_xor((int)snd.y, 32);
            uint2 lo = hi ? rcv : pA[2*ks];
            uint2 hb = hi ? pA[2*ks+1] : rcv;
            union { unsigned int u[4]; v8s vv; } cc;
            cc.u[0] = lo.x; cc.u[1] = lo.y; cc.u[2] = hb.x; cc.u[3] = hb.y;
            pf_prev[ks] = cc.vv;
        }

        // ---- bar2: counted wait — K(it+1) resident, V(it+1) in flight ----
        if (it == ITERS - 1) asm volatile("s_waitcnt vmcnt(0)" ::: "memory");
        else                 asm volatile("s_waitcnt vmcnt(4)" ::: "memory");
        __builtin_amdgcn_sched_barrier(0);
        __builtin_amdgcn_s_barrier();
    }

    // ---- final PV(ITERS-1): V in Vbuf((ITERS-1)&1) = Vbuf1 ----
    {
        const unsigned short* Vlast = &sbuf[16384 + ((ITERS - 1) & 1)*8192];
        __builtin_amdgcn_s_setprio(1);
        #pragma unroll
        for (int ks = 0; ks < 2; ++ks){
            const unsigned short* vrow = &Vlast[(2*ks + hi)*2048 + ln*8];
            #pragma unroll
            for (int t2 = 0; t2 < 8; ++t2){
                v8s av = *(const v8s*)&vrow[t2*256];
                oacc[t2] = __builtin_amdgcn_mfma_f32_32x32x16_bf16(av, pf_prev[ks], oacc[t2], 0, 0, 0);
            }
        }
        __builtin_amdgcn_s_setprio(0);
    }

    // ---- epilogue: normalize, per-wave LDS transpose, coalesced nt stores ----
    float inv = 1.0f / l_run;
    size_t orow0 = (size_t)(split*B_ + b)*S_ + qt*BM + w*32;
    if (hi == 0) lsep[orow0 + ln] = l_run;     // plain partial sum (shared base)

    unsigned short* myreg = &sbuf[(w & 1) * 8320];       // 32 rows x 260 shorts
    #pragma unroll
    for (int rnd = 0; rnd < 2; ++rnd){
        __syncthreads();
        if ((w >> 1) == rnd){
            #pragma unroll
            for (int t = 0; t < 8; ++t)
                #pragma unroll
                for (int g = 0; g < 4; ++g){
                    uint2 u;
                    u.x = pkb(oacc[t][4*g+0]*inv, oacc[t][4*g+1]*inv);
                    u.y = pkb(oacc[t][4*g+2]*inv, oacc[t][4*g+3]*inv);
                    *(uint2*)&myreg[ln*260 + t*32 + 8*g + 4*hi] = u;
                }
            #pragma unroll
            for (int p = 0; p < 16; ++p){
                int qq = 2*p + (lane >> 5);
                int ch = lane & 31;
                v4u val = *(const v4u*)&myreg[qq*260 + ch*8];
                __builtin_nontemporal_store(val,
                    (v4u*)(opart + (orow0 + qq)*D_ + ch*8));
            }
        }
    }
}

// ---------- merge the 4 K-splits (l-weighted, shared fixed base) ----------
__global__ void merge_k(const unsigned short* __restrict__ opart,
                        const float* __restrict__ lsep, float* __restrict__ out){
    int gid = blockIdx.x * 256 + threadIdx.x;   // 2048 blocks
    int row = gid >> 5;                         // b*S + q
    int dc  = (gid & 31) * 8;
    float L[4];
    #pragma unroll
    for (int s = 0; s < 4; ++s) L[s] = lsep[s*(B_*S_) + row];
    float inv = 1.0f / (L[0] + L[1] + L[2] + L[3]);
    float acc[8];
    #pragma unroll
    for (int j = 0; j < 8; ++j) acc[j] = 0.0f;
    #pragma unroll
    for (int s = 0; s < 4; ++s){
        float wgt = L[s] * inv;
        uint4 u = *(const uint4*)(opart + ((size_t)(s*(B_*S_) + row))*D_ + dc);
        acc[0] += wgt * bf2f(u.x & 0xffffu);  acc[1] += wgt * bf2f(u.x >> 16);
        acc[2] += wgt * bf2f(u.y & 0xffffu);  acc[3] += wgt * bf2f(u.y >> 16);
        acc[4] += wgt * bf2f(u.z & 0xffffu);  acc[5] += wgt * bf2f(u.z >> 16);
        acc[6] += wgt * bf2f(u.w & 0xffffu);  acc[7] += wgt * bf2f(u.w >> 16);
    }
    float* op = out + (size_t)row*D_ + dc;
    *(float4*)op       = make_float4(acc[0], acc[1], acc[2], acc[3]);
    *(float4*)(op + 4) = make_float4(acc[4], acc[5], acc[6], acc[7]);
}

extern "C" void kernel_launch(void* const* d_in, const int* in_sizes, int n_in,
                              void* d_out, int out_size, void* d_ws, size_t ws_size,
                              hipStream_t stream){
    const float* q = (const float*)d_in[0];
    const float* k = (const float*)d_in[1];
    const float* v = (const float*)d_in[2];
    char* ws = (char*)d_ws;
    // ws: Qb 8M | Kb 8M | Vt 8M | lse 256K | Opart(bf16) 32M = 58,982,400 B
    uint4* qb = (uint4*)(ws);
    uint4* kb = (uint4*)(ws + 8388608);
    uint4* vt = (uint4*)(ws + 16777216);
    float* lse = (float*)(ws + 25165824);
    unsigned short* opart = (unsigned short*)(ws + 25427968);

    cvt_all<<<dim3(1536), dim3(256), 0, stream>>>(q, k, v, qb, kb, vt);
    fa_main<<<dim3(512), dim3(256), 0, stream>>>((const unsigned short*)qb,
                                                 (const unsigned short*)kb,
                                                 (const unsigned short*)vt,
                                                 opart, lse);
    merge_k<<<dim3(2048), dim3(256), 0, stream>>>(opart, lse, (float*)d_out);
}

// Round 12
// 182.907 us; speedup vs baseline: 1.5234x; 1.1011x over previous
//
#include <hip/hip_runtime.h>
#include <hip/hip_bf16.h>

#define B_ 4
#define S_ 4096
#define D_ 256
#define BM 128
#define BN 32
#define NSPLIT 4
#define SKEYS (S_/NSPLIT)   // 1024 keys per split
#define ITERS (SKEYS/BN)    // 32

typedef short v8s __attribute__((ext_vector_type(8)));
typedef float v4f __attribute__((ext_vector_type(4)));
typedef unsigned int v4u __attribute__((ext_vector_type(4)));

__device__ __forceinline__ unsigned int pkb(float a, float b){
    __hip_bfloat162 h = __float22bfloat162_rn(make_float2(a, b));   // packed cvt
    union { __hip_bfloat162 h; unsigned int u; } c; c.h = h;
    return c.u;               // a in low 16, b in high 16
}
__device__ __forceinline__ float bf2f(unsigned int lo16){
    return __uint_as_float(lo16 << 16);
}
// async global->LDS, 16B/lane; LDS dest = wave-uniform base + lane*16
__device__ __forceinline__ void gload_lds(const unsigned short* g, unsigned short* l){
    __builtin_amdgcn_global_load_lds(
        (const __attribute__((address_space(1))) unsigned int*)g,
        (__attribute__((address_space(3))) unsigned int*)l, 16, 0, 0);
}

// ---------- fused conversion to tile-major bf16 (unchanged layouts) ----------
__global__ void cvt_all(const float* __restrict__ q, const float* __restrict__ k,
                        const float* __restrict__ v,
                        uint4* __restrict__ qb, uint4* __restrict__ kb,
                        uint4* __restrict__ vt){
    __shared__ __align__(16) unsigned short lds[8192];   // 16KB: one bf16 tile
    int bx = blockIdx.x;
    int t  = threadIdx.x;
    int which = bx >> 9;            // 0=Q, 1=K, 2=V
    int tile  = bx & 511;
    const float* srcm = (which == 0) ? q : (which == 1) ? k : v;
    const float4* src = (const float4*)(srcm + (size_t)tile * 8192);

    if (which < 2){
        const float sc = (which == 0) ? 0.09016994f : 1.0f;   // log2(e)/16 for Q
        #pragma unroll
        for (int p = 0; p < 8; ++p){
            int i = p*256 + t;                 // float4 index, coalesced
            float4 a = src[i];
            int row = i >> 6, d0 = (i & 63) * 4;
            unsigned byte = (unsigned)(row*512 + d0*2) ^ (unsigned)((row & 7) << 4);
            uint2 u; u.x = pkb(a.x*sc, a.y*sc); u.y = pkb(a.z*sc, a.w*sc);
            *(uint2*)((char*)lds + byte) = u;
        }
        __syncthreads();
        uint4* dst = ((which == 0) ? qb : kb) + (size_t)tile * 1024;
        #pragma unroll
        for (int q4 = 0; q4 < 4; ++q4){
            int o = q4*256 + t;
            int c = o >> 5, row = o & 31;
            unsigned byte = (unsigned)(row*512 + c*16) ^ (unsigned)((row & 7) << 4);
            dst[o] = *(const uint4*)((const char*)lds + byte);
        }
    } else {
        #pragma unroll
        for (int p = 0; p < 8; ++p){
            int i = p*256 + t;
            float4 a = src[i];
            uint2 u; u.x = pkb(a.x, a.y); u.y = pkb(a.z, a.w);
            *(uint2*)((char*)lds + (size_t)i*8) = u;
        }
        __syncthreads();
        uint4* dst = vt + (size_t)tile * 1024;
        #pragma unroll
        for (int q4 = 0; q4 < 4; ++q4){          // kc = q4, d = t
            union { unsigned short sh[8]; uint4 u; } cell;
            #pragma unroll
            for (int j = 0; j < 8; ++j)
                cell.sh[j] = lds[(q4*8 + j)*256 + t];
            dst[q4*256 + t] = cell.u;
        }
    }
}

// ---------- main flash-attention kernel: 8 waves x 16 q, 16x16x32 MFMA ----------
// Halved per-wave register state (qf 32 + oacc 64) doubles occupancy to
// 4 waves/SIMD (16 waves/CU at 2 blocks/CU) — the TLP that r2..r11 showed the
// 32q/wave structure (256 regs -> 2 waves/SIMD) could never have.
// Same algorithm: r9's PV-pipelined loop, K/V LDS dbuf (same tile layouts),
// counted vmcnt (2 loads per stage at 8-wave split), fixed-base exp2 softmax.
// 16x16x32 layouts (guide-verified): C/D col=lane&15 row=(lane>>4)*4+r;
// A row=lane&15, k=(lane>>4)*8+j; B col=lane&15, k=(lane>>4)*8+j.
__global__ __launch_bounds__(512, 4) void fa_main(
    const unsigned short* __restrict__ qb, const unsigned short* __restrict__ kb,
    const unsigned short* __restrict__ vtg,
    unsigned short* __restrict__ opart, float* __restrict__ lsep)
{
    // LDS: K0 | K1 | V0 | V1, 8192 shorts (16KB) each = 64KB.
    // Epilogue scratch reuses [0, 16896); final PV reads V(31&1)=V1 (24576+) — no overlap.
    __shared__ __align__(16) unsigned short sbuf[32768];

    int bid = blockIdx.x;
    int grp = bid & 15;                 // (b,split): KV group -> XCD slot
    int qt  = bid >> 4;
    int b = grp >> 2, split = grp & 3;
    int tid = threadIdx.x;
    int w = tid >> 6, lane = tid & 63;
    int qy = lane & 15, g = lane >> 4;  // 16x16 lane coords: col(q)=qy, k-group=g

    const unsigned short* kg = kb + ((size_t)(b*128 + split*32))*8192;
    const unsigned short* vg = vtg + ((size_t)(b*128 + split*32))*8192;

    // staging: wave w covers eighth [w*1024, +1024) shorts of each 16KB tile
    auto stageK = [&](int tile, int buf){
        const unsigned short* src = kg + (size_t)tile*8192 + w*1024;
        #pragma unroll
        for (int p = 0; p < 2; ++p)
            gload_lds(src + p*512 + lane*8, &sbuf[buf*8192 + w*1024 + p*512 + lane*8]);
    };
    auto stageV = [&](int tile, int buf){
        const unsigned short* src = vg + (size_t)tile*8192 + w*1024;
        #pragma unroll
        for (int p = 0; p < 2; ++p)
            gload_lds(src + p*512 + lane*8, &sbuf[16384 + buf*8192 + w*1024 + p*512 + lane*8]);
    };

    // Q direct global->reg. Wave w owns q-rows qt*128 + w*16 .. +16:
    // subtile qt*4 + (w>>1), rows (w&1)*16 + qy. B-frag s: k(d) = s*32 + g*8+j
    // -> cell c = s*4 + g, 16B contiguous per lane.
    v8s qf[8];
    {
        const unsigned short* qsrc = qb + ((size_t)(b*128 + qt*4 + (w >> 1)))*8192;
        int qrow = (w & 1)*16 + qy;
        #pragma unroll
        for (int s = 0; s < 8; ++s)
            qf[s] = *(const v8s*)&qsrc[(s*4 + g)*256 + qrow*8];
    }
    stageK(0, 0);
    stageV(0, 0);
    asm volatile("s_waitcnt vmcnt(0)" ::: "memory");
    __builtin_amdgcn_sched_barrier(0);
    __builtin_amdgcn_s_barrier();      // K(0), V(0) resident for all waves

    v4f oacc[16];
    #pragma unroll
    for (int t = 0; t < 16; ++t)
        #pragma unroll
        for (int r = 0; r < 4; ++r) oacc[t][r] = 0.0f;
    float l_run = 0.0f;
    v8s pf_prev = {};                  // set in iter 0, consumed from iter 1

    for (int it = 0; it < ITERS; ++it){
        int cur = it & 1;
        const unsigned short* Kb    = &sbuf[cur*8192];
        const unsigned short* Vprev = &sbuf[16384 + (cur ^ 1)*8192];   // (it-1)&1

        if (it + 1 < ITERS) stageK(it + 1, cur ^ 1);

        // ---- QK(it): S^T tiles (16k x 16q), kt = key half ----
        v4f ck0, ck1;
        #pragma unroll
        for (int r = 0; r < 4; ++r){ ck0[r] = 0.0f; ck1[r] = 0.0f; }
        __builtin_amdgcn_s_setprio(1);
        #pragma unroll
        for (int s = 0; s < 8; ++s){
            v8s a0 = *(const v8s*)&Kb[(s*4 + g)*256 + (     qy)*8];   // keys 0..15
            v8s a1 = *(const v8s*)&Kb[(s*4 + g)*256 + (16 + qy)*8];   // keys 16..31
            ck0 = __builtin_amdgcn_mfma_f32_16x16x32_bf16(a0, qf[s], ck0, 0, 0, 0);
            ck1 = __builtin_amdgcn_mfma_f32_16x16x32_bf16(a1, qf[s], ck1, 0, 0, 0);
        }
        __builtin_amdgcn_s_setprio(0);

        // ---- PV(it-1): independent of QK(it)/softmax(it) ----
        if (it > 0){
            __builtin_amdgcn_s_setprio(1);
            #pragma unroll
            for (int dt = 0; dt < 16; ++dt){
                v8s av = *(const v8s*)&Vprev[g*2048 + (dt*16 + qy)*8];
                oacc[dt] = __builtin_amdgcn_mfma_f32_16x16x32_bf16(av, pf_prev, oacc[dt], 0, 0, 0);
            }
            __builtin_amdgcn_s_setprio(0);
        }

        // ---- bar1: all waves done reading Vbuf((it-1)&1) -> safe to restage ----
        __builtin_amdgcn_s_barrier();
        if (it + 1 < ITERS) stageV(it + 1, cur ^ 1);

        // ---- fixed-base softmax: P = exp2(S). Lane holds k = kt*16 + g*4 + r,
        //      q = qy. Row-sum: 2 xor-shuffles across the 4 k-groups. ----
        float e00 = exp2f(ck0[0]), e01 = exp2f(ck0[1]);
        float e02 = exp2f(ck0[2]), e03 = exp2f(ck0[3]);
        float e10 = exp2f(ck1[0]), e11 = exp2f(ck1[1]);
        float e12 = exp2f(ck1[2]), e13 = exp2f(ck1[3]);
        float ls = ((e00 + e01) + (e02 + e03)) + ((e10 + e11) + (e12 + e13));
        ls += __shfl_xor(ls, 16);
        ls += __shfl_xor(ls, 32);
        l_run += ls;

        // ---- P: C-layout -> B-operand. Target lane g needs keys 8g..8g+7;
        //      sources: lane qy+32(g&1) (first 4) and +16 (next 4), half kt=g>>1.
        unsigned A0 = pkb(e00, e01), B0 = pkb(e02, e03);
        unsigned A1 = pkb(e10, e11), B1 = pkb(e12, e13);
        {
            int sA = qy + ((g & 1) << 5);
            int sB = sA + 16;
            int ktsel = g >> 1;
            unsigned u0a = (unsigned)__shfl((int)A0, sA);
            unsigned u0b = (unsigned)__shfl((int)A1, sA);
            unsigned u1a = (unsigned)__shfl((int)B0, sA);
            unsigned u1b = (unsigned)__shfl((int)B1, sA);
            unsigned u2a = (unsigned)__shfl((int)A0, sB);
            unsigned u2b = (unsigned)__shfl((int)A1, sB);
            unsigned u3a = (unsigned)__shfl((int)B0, sB);
            unsigned u3b = (unsigned)__shfl((int)B1, sB);
            union { unsigned u[4]; v8s v; } cc;
            cc.u[0] = ktsel ? u0b : u0a;
            cc.u[1] = ktsel ? u1b : u1a;
            cc.u[2] = ktsel ? u2b : u2a;
            cc.u[3] = ktsel ? u3b : u3a;
            pf_prev = cc.v;
        }

        // ---- bar2: counted wait — K(it+1) resident, V(it+1) (2 loads) in flight ----
        if (it == ITERS - 1) asm volatile("s_waitcnt vmcnt(0)" ::: "memory");
        else                 asm volatile("s_waitcnt vmcnt(2)" ::: "memory");
        __builtin_amdgcn_sched_barrier(0);
        __builtin_amdgcn_s_barrier();
    }

    // ---- final PV(ITERS-1): V in Vbuf((ITERS-1)&1) = Vbuf1 ----
    {
        const unsigned short* Vlast = &sbuf[16384 + ((ITERS - 1) & 1)*8192];
        __builtin_amdgcn_s_setprio(1);
        #pragma unroll
        for (int dt = 0; dt < 16; ++dt){
            v8s av = *(const v8s*)&Vlast[g*2048 + (dt*16 + qy)*8];
            oacc[dt] = __builtin_amdgcn_mfma_f32_16x16x32_bf16(av, pf_prev, oacc[dt], 0, 0, 0);
        }
        __builtin_amdgcn_s_setprio(0);
    }

    // ---- epilogue: normalize, per-wave LDS transpose, coalesced nt stores ----
    // Lane holds O^T[d = dt*16 + g*4 + r][q = qy]; l_run is the full row-sum
    // for q = qy (replicated across groups). Two rounds of 4 waves; per-wave
    // region 16 rows x 264 shorts (pad 8 -> write banks spread 4r, 2-way max).
    float inv = 1.0f / l_run;
    size_t orow0 = (size_t)(split*B_ + b)*S_ + qt*BM + w*16;
    if (g == 0) lsep[orow0 + qy] = l_run;

    unsigned short* myreg = &sbuf[(w & 3) * 4224];       // 16 rows x 264 shorts
    #pragma unroll
    for (int rnd = 0; rnd < 2; ++rnd){
        __syncthreads();
        if ((w >> 2) == rnd){
            #pragma unroll
            for (int dt = 0; dt < 16; ++dt){
                uint2 u;
                u.x = pkb(oacc[dt][0]*inv, oacc[dt][1]*inv);
                u.y = pkb(oacc[dt][2]*inv, oacc[dt][3]*inv);
                *(uint2*)&myreg[qy*264 + dt*16 + 4*g] = u;
            }
            #pragma unroll
            for (int p = 0; p < 8; ++p){
                int qq = 2*p + (lane >> 5);
                int ch = lane & 31;
                v4u val = *(const v4u*)&myreg[qq*264 + ch*8];
                __builtin_nontemporal_store(val,
                    (v4u*)(opart + (orow0 + qq)*D_ + ch*8));
            }
        }
    }
}

// ---------- merge the 4 K-splits (l-weighted, shared fixed base) ----------
__global__ void merge_k(const unsigned short* __restrict__ opart,
                        const float* __restrict__ lsep, float* __restrict__ out){
    int gid = blockIdx.x * 256 + threadIdx.x;   // 2048 blocks
    int row = gid >> 5;                         // b*S + q
    int dc  = (gid & 31) * 8;
    float L[4];
    #pragma unroll
    for (int s = 0; s < 4; ++s) L[s] = lsep[s*(B_*S_) + row];
    float inv = 1.0f / (L[0] + L[1] + L[2] + L[3]);
    float acc[8];
    #pragma unroll
    for (int j = 0; j < 8; ++j) acc[j] = 0.0f;
    #pragma unroll
    for (int s = 0; s < 4; ++s){
        float wgt = L[s] * inv;
        uint4 u = *(const uint4*)(opart + ((size_t)(s*(B_*S_) + row))*D_ + dc);
        acc[0] += wgt * bf2f(u.x & 0xffffu);  acc[1] += wgt * bf2f(u.x >> 16);
        acc[2] += wgt * bf2f(u.y & 0xffffu);  acc[3] += wgt * bf2f(u.y >> 16);
        acc[4] += wgt * bf2f(u.z & 0xffffu);  acc[5] += wgt * bf2f(u.z >> 16);
        acc[6] += wgt * bf2f(u.w & 0xffffu);  acc[7] += wgt * bf2f(u.w >> 16);
    }
    float* op = out + (size_t)row*D_ + dc;
    *(float4*)op       = make_float4(acc[0], acc[1], acc[2], acc[3]);
    *(float4*)(op + 4) = make_float4(acc[4], acc[5], acc[6], acc[7]);
}

extern "C" void kernel_launch(void* const* d_in, const int* in_sizes, int n_in,
                              void* d_out, int out_size, void* d_ws, size_t ws_size,
                              hipStream_t stream){
    const float* q = (const float*)d_in[0];
    const float* k = (const float*)d_in[1];
    const float* v = (const float*)d_in[2];
    char* ws = (char*)d_ws;
    // ws: Qb 8M | Kb 8M | Vt 8M | lse 256K | Opart(bf16) 32M = 58,982,400 B
    uint4* qb = (uint4*)(ws);
    uint4* kb = (uint4*)(ws + 8388608);
    uint4* vt = (uint4*)(ws + 16777216);
    float* lse = (float*)(ws + 25165824);
    unsigned short* opart = (unsigned short*)(ws + 25427968);

    cvt_all<<<dim3(1536), dim3(256), 0, stream>>>(q, k, v, qb, kb, vt);
    fa_main<<<dim3(512), dim3(512), 0, stream>>>((const unsigned short*)qb,
                                                 (const unsigned short*)kb,
                                                 (const unsigned short*)vt,
                                                 opart, lse);
    merge_k<<<dim3(2048), dim3(256), 0, stream>>>(opart, lse, (float*)d_out);
}